// Round 8
// baseline (83.632 us; speedup 1.0000x reference)
//
#include <hip/hip_runtime.h>
#include <hip/hip_bf16.h>

#define T_ 64
#define S_ 64
#define B_ 128
#define E_ 64
#define H_ 4

typedef float f32x4 __attribute__((ext_vector_type(4)));
typedef short bf16x8 __attribute__((ext_vector_type(8)));

static __device__ __forceinline__ short f2b(float f) {
    union { __hip_bfloat16 h; short s; } u;
    u.h = __float2bfloat16(f);
    return u.s;
}

// ---------------------------------------------------------------------------
// K1: qkv projection. qkv layout: [3][T][B][E].
// Block 256 instead preps relW as bf16 fragment-linear (16 KB) into ws so
// k_logits waves can load B fragments straight from global (L1/L2-hot),
// with no per-wg staging, no LDS, no barriers.
// ---------------------------------------------------------------------------
__global__ __launch_bounds__(256) void k_qkv(
    const float* __restrict__ qin, const float* __restrict__ kin,
    const float* __restrict__ vin, const float* __restrict__ W,
    const float* __restrict__ bias, float* __restrict__ qkv,
    const float* __restrict__ relW, ushort* __restrict__ wBf)
{
    const int tid = threadIdx.x;

    if (blockIdx.x == 256) {
        // prep: relW [128][64] fp32 -> bf16 fragment-linear.
        // fragment (ot,ks) at ushort offset (ot*2+ks)*512 + lane*8, where
        // lane (c,rq) holds row o=ot*16+c, elems e=ks*32+rq*8..+7.
        #pragma unroll
        for (int li = 0; li < 8; ++li) {
            int f4 = li * 256 + tid;             // 0..2047 = o*16 + e4
            int o = f4 >> 4, e4 = f4 & 15;
            float4 wv = reinterpret_cast<const float4*>(relW)[f4];
            ushort4 bv;
            bv.x = (ushort)f2b(wv.x); bv.y = (ushort)f2b(wv.y);
            bv.z = (ushort)f2b(wv.z); bv.w = (ushort)f2b(wv.w);
            int ot = o >> 4, cc = o & 15;
            int ks = e4 >> 3, rqb = (e4 & 7) >> 1, half = e4 & 1;
            int dest = (ot * 2 + ks) * 512 + (rqb * 16 + cc) * 8 + half * 4;
            *reinterpret_cast<ushort4*>(wBf + dest) = bv;
        }
        return;
    }

    __shared__ float xs[3][32 * 68];
    __shared__ float WTs[64 * 68];
    const int row0 = blockIdx.x * 32;

    #pragma unroll
    for (int l = 0; l < 6; ++l) {
        int f4 = l * 256 + tid;
        int src = f4 >> 9, rem = f4 & 511;
        int r = rem >> 4, e0 = (rem & 15) << 2;
        const float* xin = (src == 0) ? qin : (src == 1 ? kin : vin);
        float4 xv = reinterpret_cast<const float4*>(xin)[(size_t)(row0 + r) * 16 + (e0 >> 2)];
        float* dst = &xs[src][r * 68];
        dst[e0] = xv.x; dst[e0 + 1] = xv.y; dst[e0 + 2] = xv.z; dst[e0 + 3] = xv.w;
    }

    const int rq = tid >> 5, og = tid & 31;
    const int r0 = rq * 4, op0 = og * 2;

    for (int seg = 0; seg < 3; ++seg) {
        __syncthreads();
        #pragma unroll
        for (int l = 0; l < 4; ++l) {
            int f4 = l * 256 + tid;
            int o = f4 >> 4, e0 = (f4 & 15) << 2;
            float4 wv = reinterpret_cast<const float4*>(W)[(size_t)(seg * 64 + o) * 16 + (e0 >> 2)];
            WTs[(e0 + 0) * 68 + o] = wv.x; WTs[(e0 + 1) * 68 + o] = wv.y;
            WTs[(e0 + 2) * 68 + o] = wv.z; WTs[(e0 + 3) * 68 + o] = wv.w;
        }
        __syncthreads();

        float acc[4][2];
        #pragma unroll
        for (int rr = 0; rr < 4; ++rr) {
            acc[rr][0] = bias[seg * 64 + op0];
            acc[rr][1] = bias[seg * 64 + op0 + 1];
        }
        const float* xsrc = xs[seg];
        #pragma unroll 4
        for (int e = 0; e < 64; ++e) {
            float w0 = WTs[e * 68 + op0];
            float w1 = WTs[e * 68 + op0 + 1];
            #pragma unroll
            for (int rr = 0; rr < 4; ++rr) {
                float xv = xsrc[(r0 + rr) * 68 + e];
                acc[rr][0] += xv * w0;
                acc[rr][1] += xv * w1;
            }
        }
        #pragma unroll
        for (int rr = 0; rr < 4; ++rr) {
            float2 ov = make_float2(acc[rr][0], acc[rr][1]);
            reinterpret_cast<float2*>(
                &qkv[((size_t)seg * T_ * B_ + row0 + r0 + rr) * E_ + op0])[0] = ov;
        }
    }
}

// ---------------------------------------------------------------------------
// K2a: fused relation-projection + logits. Flat max-TLP, one-shot wave units.
// grid = 64 i * 64 j * 2 g = 8192 wgs, 256 thr = 4 waves; wave w = unit
// (i, j, btile = g*4+w). NO LDS, NO barriers, no loops: A (4 float4, HBM)
// -> B (16 bf16x8 direct from prepped global buffer, L1-hot) -> 16 MFMA ->
// kvv/qpre (L2, loaded after MFMA to cap peak regs ~100) -> butterfly
// reduce-scatter -> one coalesced 256 B store to logits[i][j][b][h].
// __launch_bounds__(256, 4): 16 waves/CU, 128-VGPR cap (both arg2
// interpretations agree). BW floor: 512 KB/CU A-stream ~= 21 us.
// ---------------------------------------------------------------------------
__global__ __launch_bounds__(256, 4) void k_logits_mfma(
    const float* __restrict__ rel, const ushort* __restrict__ wBf,
    const float* __restrict__ relBias, const float* __restrict__ qkv,
    float* __restrict__ logits)
{
    const int tid = threadIdx.x;
    const int w   = tid >> 6;
    const int l   = tid & 63;
    const int c   = l & 15;      // MFMA col lane
    const int rq  = l >> 4;      // MFMA row-quadrant / k-subchunk
    const int g   = blockIdx.x & 1;
    const int j   = (blockIdx.x >> 1) & 63;
    const int i   = blockIdx.x >> 7;
    const int btile = g * 4 + w;

    // ---- A loads first (HBM/L3 long pole) ----
    const int arow = ((btile * 16 + c) * E_) + rq * 8;
    float4 a0, a1, a2, a3;
    {
        const float* ab = rel + ((size_t)j * S_ + i) * (size_t)(B_ * E_) + arow;
        a0 = *(const float4*)(ab);
        a1 = *(const float4*)(ab + 4);
        a2 = *(const float4*)(ab + 32);
        a3 = *(const float4*)(ab + 36);
    }

    // ---- B fragments direct from global (identical for all wgs; L1-hot) ----
    bf16x8 bfr[8][2];
    #pragma unroll
    for (int ot = 0; ot < 8; ++ot)
        #pragma unroll
        for (int ks = 0; ks < 2; ++ks)
            bfr[ot][ks] = *(const bf16x8*)(wBf + (ot * 2 + ks) * 512 + l * 8);

    // ---- cvt A to bf16 fragments ----
    bf16x8 af0, af1;
    {
        bf16x8 a;
        a[0] = f2b(a0.x); a[1] = f2b(a0.y); a[2] = f2b(a0.z); a[3] = f2b(a0.w);
        a[4] = f2b(a1.x); a[5] = f2b(a1.y); a[6] = f2b(a1.z); a[7] = f2b(a1.w);
        af0 = a;
        a[0] = f2b(a2.x); a[1] = f2b(a2.y); a[2] = f2b(a2.z); a[3] = f2b(a2.w);
        a[4] = f2b(a3.x); a[5] = f2b(a3.y); a[6] = f2b(a3.z); a[7] = f2b(a3.w);
        af1 = a;
    }

    // ---- GEMM: 8 o-tiles x 2 k-steps ----
    f32x4 acc[8];
    #pragma unroll
    for (int ot = 0; ot < 8; ++ot) acc[ot] = (f32x4){0.f, 0.f, 0.f, 0.f};
    #pragma unroll
    for (int ot = 0; ot < 8; ++ot) {
        acc[ot] = __builtin_amdgcn_mfma_f32_16x16x32_bf16(af0, bfr[ot][0], acc[ot], 0, 0, 0);
        acc[ot] = __builtin_amdgcn_mfma_f32_16x16x32_bf16(af1, bfr[ot][1], acc[ot], 0, 0, 0);
    }

    // ---- epilogue operands (L2-hot), loaded late to keep peak regs low ----
    float qpre[4][4], bbv[4], kvv[4][4];
    {
        const float* qrow = qkv + (size_t)i * (B_ * E_);
        const float* krow = qkv + ((size_t)(T_ * B_) + (size_t)j * B_ + btile * 16 + rq * 4) * E_;
        #pragma unroll
        for (int h = 0; h < 4; ++h) {
            float ba = relBias[h * 16 + c];
            bbv[h] = relBias[64 + h * 16 + c];
            #pragma unroll
            for (int r = 0; r < 4; ++r) {
                int b = btile * 16 + rq * 4 + r;
                qpre[h][r] = qrow[b * E_ + h * 16 + c] + ba;
                kvv[h][r] = krow[r * E_ + h * 16 + c];
            }
        }
    }

    // ---- butterfly reduce-scatter over c-lanes ----
    float v[16];
    #pragma unroll
    for (int h = 0; h < 4; ++h)
        #pragma unroll
        for (int r = 0; r < 4; ++r)
            v[h * 4 + r] = (qpre[h][r] + acc[h][r]) *
                           (kvv[h][r] + bbv[h] + acc[4 + h][r]);
    #pragma unroll
    for (int k = 0; k < 8; ++k) {
        float x = (c & 1) ? v[2 * k + 1] : v[2 * k];
        float y = (c & 1) ? v[2 * k] : v[2 * k + 1];
        v[k] = x + __shfl_xor(y, 1);
    }
    #pragma unroll
    for (int k = 0; k < 4; ++k) {
        float x = (c & 2) ? v[2 * k + 1] : v[2 * k];
        float y = (c & 2) ? v[2 * k] : v[2 * k + 1];
        v[k] = x + __shfl_xor(y, 2);
    }
    #pragma unroll
    for (int k = 0; k < 2; ++k) {
        float x = (c & 4) ? v[2 * k + 1] : v[2 * k];
        float y = (c & 4) ? v[2 * k] : v[2 * k + 1];
        v[k] = x + __shfl_xor(y, 4);
    }
    float outv;
    {
        float x = (c & 8) ? v[1] : v[0];
        float y = (c & 8) ? v[0] : v[1];
        outv = (x + __shfl_xor(y, 8)) * 0.0625f;
    }

    // ---- coalesced store: b = btile*16+rq*4+(c&3), h = c>>2 ----
    {
        const int off = btile * 64 + rq * 16 + (c & 3) * 4 + (c >> 2);
        logits[((size_t)i * S_ + j) * (B_ * H_) + off] = outv;
    }
}

// ---------------------------------------------------------------------------
// K2b: softmax over j + PV + out-projection. logits layout [i][j][b][h];
// block (i, bq) loads its 64 j x 16 (b,h) slab coalesced (64 B rows) into a
// [64][20] LDS tile (aligned float4 writes, <=2-way banks), then softmax/PV
// as before.
// ---------------------------------------------------------------------------
__global__ __launch_bounds__(256) void k_attn(
    const float* __restrict__ logits, const float* __restrict__ qkv,
    const float* __restrict__ Wout, const float* __restrict__ bout,
    float* __restrict__ out)
{
    __shared__ float trans[64][20];
    __shared__ float wsm[4][H_][S_];
    __shared__ float ap[4][68];
    const int tid = threadIdx.x;
    const int i = blockIdx.x >> 5;
    const int bq = blockIdx.x & 31;
    const int w = tid >> 6, l = tid & 63;
    const int b = bq * 4 + w;

    // load slab: thread p -> j = p>>2, quarter q = p&3 (float4 of 16-float row)
    {
        const int jj = tid >> 2, q = tid & 3;
        float4 lv = *(const float4*)(logits + ((size_t)i * S_ + jj) * (B_ * H_) + bq * 16 + q * 4);
        *reinterpret_cast<float4*>(&trans[jj][q * 4]) = lv;
    }
    __syncthreads();

    // softmax: lane (h = l>>4, sub = l&15); col = w*4 + h
    const int h = l >> 4, sub = l & 15;
    const int col = w * 4 + h;
    float v0 = trans[sub][col];
    float v1 = trans[sub + 16][col];
    float v2 = trans[sub + 32][col];
    float v3 = trans[sub + 48][col];
    float m = fmaxf(fmaxf(v0, v1), fmaxf(v2, v3));
    #pragma unroll
    for (int d = 1; d < 16; d <<= 1) m = fmaxf(m, __shfl_xor(m, d));
    float e0 = expf(v0 - m), e1 = expf(v1 - m), e2 = expf(v2 - m), e3 = expf(v3 - m);
    float ss = e0 + e1 + e2 + e3;
    #pragma unroll
    for (int d = 1; d < 16; d <<= 1) ss += __shfl_xor(ss, d);
    float inv = 1.0f / ss;
    wsm[w][h][sub] = e0 * inv;
    wsm[w][h][sub + 16] = e1 * inv;
    wsm[w][h][sub + 32] = e2 * inv;
    wsm[w][h][sub + 48] = e3 * inv;
    __syncthreads();

    const float* vbase = qkv + (size_t)2 * T_ * B_ * E_ + (size_t)b * E_;
    const float* wrow = &wsm[w][l >> 4][0];
    float acc = 0.f;
    #pragma unroll 4
    for (int j = 0; j < S_; ++j) acc += wrow[j] * vbase[(size_t)j * B_ * E_ + l];
    ap[w][l] = acc;
    __syncthreads();

    const float* wo = Wout + l * E_;
    const float* apw = ap[w];
    float oacc = bout[l];
    #pragma unroll 4
    for (int e = 0; e < E_; ++e) oacc += apw[e] * wo[e];
    out[((size_t)i * B_ + b) * E_ + l] = oacc;
}

// ---------------------------------------------------------------------------
extern "C" void kernel_launch(void* const* d_in, const int* in_sizes, int n_in,
                              void* d_out, int out_size, void* d_ws, size_t ws_size,
                              hipStream_t stream)
{
    const float* qin = (const float*)d_in[0];
    const float* kin = (const float*)d_in[1];
    const float* vin = (const float*)d_in[2];
    const float* rel = (const float*)d_in[3];
    const float* ipw = (const float*)d_in[4];
    const float* ipb = (const float*)d_in[5];
    const float* rw  = (const float*)d_in[6];
    const float* rb  = (const float*)d_in[7];
    const float* ow  = (const float*)d_in[8];
    const float* obias = (const float*)d_in[9];

    float* qkv = (float*)d_ws;                        // 3*64*128*64 fl = 6 MB
    float* logits = qkv + 3 * T_ * B_ * E_;           // [i][j][b][h]  = 8 MB
    ushort* wBf = (ushort*)(logits + (size_t)T_ * S_ * B_ * H_);  // 16 KB

    float* out = (float*)d_out;

    k_qkv<<<dim3(257), dim3(256), 0, stream>>>(qin, kin, vin, ipw, ipb, qkv, rw, wBf);
    k_logits_mfma<<<dim3(8192), dim3(256), 0, stream>>>(rel, wBf, rb, qkv, logits);
    k_attn<<<dim3(2048), dim3(256), 0, stream>>>(logits, qkv, ow, obias, out);
}

// Round 9
// 66.079 us; speedup vs baseline: 1.2656x; 1.2656x over previous
//
#include <hip/hip_runtime.h>
#include <hip/hip_bf16.h>

#define T_ 64
#define S_ 64
#define B_ 128
#define E_ 64
#define H_ 4

typedef float f32x4 __attribute__((ext_vector_type(4)));
typedef short bf16x8 __attribute__((ext_vector_type(8)));

static __device__ __forceinline__ short f2b(float f) {
    union { __hip_bfloat16 h; short s; } u;
    u.h = __float2bfloat16(f);
    return u.s;
}

// ---------------------------------------------------------------------------
// K1: qkv projection. qkv layout: [3][T][B][E].
// Extras: (a) block 256 preps relW bf16 fragment-linear (frags 0..15) plus 4
// shifted-identity frags (16..19) into wBf; (b) the seg==1 (k) path also
// emits kpb[j] = (k + rel_bias_b) as bf16 A-operand fragment pages (16 KB/j)
// so k_logits' j-loop needs NO scalar k loads (folded into MFMA via the
// identity k-step).
// ---------------------------------------------------------------------------
__global__ __launch_bounds__(256) void k_qkv(
    const float* __restrict__ qin, const float* __restrict__ kin,
    const float* __restrict__ vin, const float* __restrict__ W,
    const float* __restrict__ bias, float* __restrict__ qkv,
    const float* __restrict__ relW, const float* __restrict__ relBias,
    ushort* __restrict__ wBf, unsigned int* __restrict__ kpbW)
{
    const int tid = threadIdx.x;

    if (blockIdx.x == 256) {
        // (a) relW [128][64] fp32 -> bf16 fragment-linear, frags fi=0..15:
        // fi=(ot*2+ks): lane (c,rq) holds W[o=ot*16+c][k=ks*32+rq*8+e].
        #pragma unroll
        for (int li = 0; li < 8; ++li) {
            int f4 = li * 256 + tid;             // 0..2047 = o*16 + e4
            int o = f4 >> 4, e4 = f4 & 15;
            float4 wv = reinterpret_cast<const float4*>(relW)[f4];
            ushort4 bv;
            bv.x = (ushort)f2b(wv.x); bv.y = (ushort)f2b(wv.y);
            bv.z = (ushort)f2b(wv.z); bv.w = (ushort)f2b(wv.w);
            int ot = o >> 4, cc = o & 15;
            int ks = e4 >> 3, rqb = (e4 & 7) >> 1, half = e4 & 1;
            int dest = (ot * 2 + ks) * 512 + (rqb * 16 + cc) * 8 + half * 4;
            *reinterpret_cast<ushort4*>(wBf + dest) = bv;
        }
        // (b) shifted-identity B-frags fi=16..19: frag ot has B[o=ot*16+c][k]
        // = 1 at local k (within its 32-half) == (ot&1)*16 + c.
        #pragma unroll
        for (int li = 0; li < 8; ++li) {
            int t = li * 256 + tid;              // 0..2047
            int ot = t >> 9, lane = (t >> 3) & 63, e = t & 7;
            int cI = lane & 15, rqI = lane >> 4;
            wBf[8192 + t] =
                (rqI * 8 + e == (ot & 1) * 16 + cI) ? (ushort)0x3F80 : (ushort)0;
        }
        return;
    }

    __shared__ float xs[3][32 * 68];
    __shared__ float WTs[64 * 68];
    const int row0 = blockIdx.x * 32;

    #pragma unroll
    for (int l = 0; l < 6; ++l) {
        int f4 = l * 256 + tid;
        int src = f4 >> 9, rem = f4 & 511;
        int r = rem >> 4, e0 = (rem & 15) << 2;
        const float* xin = (src == 0) ? qin : (src == 1 ? kin : vin);
        float4 xv = reinterpret_cast<const float4*>(xin)[(size_t)(row0 + r) * 16 + (e0 >> 2)];
        float* dst = &xs[src][r * 68];
        dst[e0] = xv.x; dst[e0 + 1] = xv.y; dst[e0 + 2] = xv.z; dst[e0 + 3] = xv.w;
    }

    const int rq = tid >> 5, og = tid & 31;
    const int r0 = rq * 4, op0 = og * 2;

    for (int seg = 0; seg < 3; ++seg) {
        __syncthreads();
        #pragma unroll
        for (int l = 0; l < 4; ++l) {
            int f4 = l * 256 + tid;
            int o = f4 >> 4, e0 = (f4 & 15) << 2;
            float4 wv = reinterpret_cast<const float4*>(W)[(size_t)(seg * 64 + o) * 16 + (e0 >> 2)];
            WTs[(e0 + 0) * 68 + o] = wv.x; WTs[(e0 + 1) * 68 + o] = wv.y;
            WTs[(e0 + 2) * 68 + o] = wv.z; WTs[(e0 + 3) * 68 + o] = wv.w;
        }
        __syncthreads();

        float acc[4][2];
        #pragma unroll
        for (int rr = 0; rr < 4; ++rr) {
            acc[rr][0] = bias[seg * 64 + op0];
            acc[rr][1] = bias[seg * 64 + op0 + 1];
        }
        const float* xsrc = xs[seg];
        #pragma unroll 4
        for (int e = 0; e < 64; ++e) {
            float w0 = WTs[e * 68 + op0];
            float w1 = WTs[e * 68 + op0 + 1];
            #pragma unroll
            for (int rr = 0; rr < 4; ++rr) {
                float xv = xsrc[(r0 + rr) * 68 + e];
                acc[rr][0] += xv * w0;
                acc[rr][1] += xv * w1;
            }
        }
        #pragma unroll
        for (int rr = 0; rr < 4; ++rr) {
            float2 ov = make_float2(acc[rr][0], acc[rr][1]);
            reinterpret_cast<float2*>(
                &qkv[((size_t)seg * T_ * B_ + row0 + r0 + rr) * E_ + op0])[0] = ov;
        }
        if (seg == 1) {
            // emit kpb = k + bb as bf16 A-frag pages: page j (8192 ushorts):
            // off = ks*4096 + (b>>4)*512 + ((b&15) + rq*16)*8 + (k&7)
            #pragma unroll
            for (int rr = 0; rr < 4; ++rr) {
                int row = row0 + r0 + rr;         // = j*128 + b
                int jj = row >> 7, b = row & 127;
                float kb0 = acc[rr][0] + relBias[64 + op0];
                float kb1 = acc[rr][1] + relBias[64 + op0 + 1];
                unsigned int u = (unsigned int)(ushort)f2b(kb0) |
                                 ((unsigned int)(ushort)f2b(kb1) << 16);
                int off = jj * 8192 + (op0 >> 5) * 4096 + (b >> 4) * 512 +
                          ((b & 15) + ((op0 & 31) >> 3) * 16) * 8 + (op0 & 7);
                kpbW[off >> 1] = u;
            }
        }
    }
}

// ---------------------------------------------------------------------------
// K2a: fused relation-projection + logits (MFMA, augmented-K j-loop).
// grid = 64 i * 8 jq = 512 wgs, 512 thr = 8 waves; (512,2) -> 2 wg/CU,
// 16 waves/CU, 128-VGPR cap (~110 used). Wave w owns b-tile w for 8 j's.
// Per j the ONLY vmem are 4 rel loads (HBM) + 2 kpb-frag loads (L2), all
// MFMA operands in clean issue order (kf(t) issued before prefetch a(t+1),
// so no wait ever drains a younger prefetch). B fragments (W_a | W_b |
// shifted-I) read from LDS per use (lgkmcnt domain - no vmcnt interference);
// an opaque-offset asm guard stops LICM from hoisting them into 80 regs.
// P_b = W_b.rel + (k+bb) comes out of the MFMA directly (identity k-step),
// so the epilogue is pure register math + butterfly reduce-scatter.
// ---------------------------------------------------------------------------
__global__ __launch_bounds__(512, 2) void k_logits_mfma(
    const float* __restrict__ rel, const ushort* __restrict__ wBf,
    const ushort* __restrict__ kpbF, const float* __restrict__ relBias,
    const float* __restrict__ qkv, float* __restrict__ logits)
{
    __shared__ char  Bs[20480];        // 20 B-frags (16 W + 4 I), 1 KB each
    __shared__ float llds[8][64][9];   // per-lane logit buffer (stride 9)

    const int tid = threadIdx.x;
    const int w = tid >> 6, l = tid & 63;
    const int c = l & 15, rq = l >> 4;
    const int i = blockIdx.x >> 3;
    const int jb = (blockIdx.x & 7) * 8;

    // stage Bs (20 KB linear copy)
    #pragma unroll
    for (int li = 0; li < 3; ++li) {
        int idx = li * 512 + tid;
        if (idx < 1280)
            reinterpret_cast<float4*>(Bs)[idx] =
                reinterpret_cast<const float4*>(wBf)[idx];
    }

    // hoist qpre = q + ba (j-invariant)
    float qpre[4][4];
    {
        const float* qrow = qkv + (size_t)i * (B_ * E_);
        #pragma unroll
        for (int h = 0; h < 4; ++h) {
            float ba = relBias[h * 16 + c];
            #pragma unroll
            for (int r = 0; r < 4; ++r)
                qpre[h][r] = qrow[(w * 16 + rq * 4 + r) * E_ + h * 16 + c] + ba;
        }
    }
    __syncthreads();

    const int arow = (w * 16 + c) * E_ + rq * 8;
    const int kfo  = w * 512 + l * 8;

    float4 x0, x1, x2, x3;
    {
        const float* ab = rel + ((size_t)jb * S_ + i) * (size_t)(B_ * E_) + arow;
        x0 = *(const float4*)(ab);
        x1 = *(const float4*)(ab + 4);
        x2 = *(const float4*)(ab + 32);
        x3 = *(const float4*)(ab + 36);
    }

    #pragma unroll 1
    for (int t = 0; t < 8; ++t) {
        const int j = jb + t;

        // kpb A-frags for this j (bf16, no cvt needed); issued BEFORE the
        // next prefetch so waiting on them never drains younger loads.
        bf16x8 kf0 = *(const bf16x8*)(kpbF + (size_t)j * 8192 + kfo);
        bf16x8 kf1 = *(const bf16x8*)(kpbF + (size_t)j * 8192 + 4096 + kfo);

        // cvt this j's A (waits on x-loads issued last iteration)
        bf16x8 af0, af1;
        {
            bf16x8 a;
            a[0] = f2b(x0.x); a[1] = f2b(x0.y); a[2] = f2b(x0.z); a[3] = f2b(x0.w);
            a[4] = f2b(x1.x); a[5] = f2b(x1.y); a[6] = f2b(x1.z); a[7] = f2b(x1.w);
            af0 = a;
            a[0] = f2b(x2.x); a[1] = f2b(x2.y); a[2] = f2b(x2.z); a[3] = f2b(x2.w);
            a[4] = f2b(x3.x); a[5] = f2b(x3.y); a[6] = f2b(x3.z); a[7] = f2b(x3.w);
            af1 = a;
        }

        // prefetch next j's A (lands during MFMA + epilogue of this j)
        if (t < 7) {
            const float* ab = rel + ((size_t)(j + 1) * S_ + i) * (size_t)(B_ * E_) + arow;
            x0 = *(const float4*)(ab);
            x1 = *(const float4*)(ab + 4);
            x2 = *(const float4*)(ab + 32);
            x3 = *(const float4*)(ab + 36);
        }

        // opaque offset: stops LICM from hoisting the 20 B-frag LDS reads
        int bs0 = 0;
        asm volatile("" : "+v"(bs0));
        const char* bsp = Bs + bs0;

        f32x4 acc[8];
        #pragma unroll
        for (int ot = 0; ot < 8; ++ot) acc[ot] = (f32x4){0.f, 0.f, 0.f, 0.f};
        #pragma unroll
        for (int ot = 0; ot < 4; ++ot) {   // pa = W_a . rel
            acc[ot] = __builtin_amdgcn_mfma_f32_16x16x32_bf16(
                af0, *(const bf16x8*)(bsp + (ot * 2 + 0) * 1024 + l * 16), acc[ot], 0, 0, 0);
            acc[ot] = __builtin_amdgcn_mfma_f32_16x16x32_bf16(
                af1, *(const bf16x8*)(bsp + (ot * 2 + 1) * 1024 + l * 16), acc[ot], 0, 0, 0);
        }
        #pragma unroll
        for (int ot = 0; ot < 4; ++ot) {   // pb = W_b . rel + (k+bb) via I-step
            acc[4 + ot] = __builtin_amdgcn_mfma_f32_16x16x32_bf16(
                af0, *(const bf16x8*)(bsp + (8 + ot * 2 + 0) * 1024 + l * 16), acc[4 + ot], 0, 0, 0);
            acc[4 + ot] = __builtin_amdgcn_mfma_f32_16x16x32_bf16(
                af1, *(const bf16x8*)(bsp + (8 + ot * 2 + 1) * 1024 + l * 16), acc[4 + ot], 0, 0, 0);
            acc[4 + ot] = __builtin_amdgcn_mfma_f32_16x16x32_bf16(
                (ot < 2 ? kf0 : kf1),
                *(const bf16x8*)(bsp + (16 + ot) * 1024 + l * 16), acc[4 + ot], 0, 0, 0);
        }

        // epilogue: v[h*4+r]; butterfly reduce-scatter over c-lanes
        float v[16];
        #pragma unroll
        for (int h = 0; h < 4; ++h)
            #pragma unroll
            for (int r = 0; r < 4; ++r)
                v[h * 4 + r] = (qpre[h][r] + acc[h][r]) * acc[4 + h][r];
        #pragma unroll
        for (int k = 0; k < 8; ++k) {
            float x = (c & 1) ? v[2 * k + 1] : v[2 * k];
            float y = (c & 1) ? v[2 * k] : v[2 * k + 1];
            v[k] = x + __shfl_xor(y, 1);
        }
        #pragma unroll
        for (int k = 0; k < 4; ++k) {
            float x = (c & 2) ? v[2 * k + 1] : v[2 * k];
            float y = (c & 2) ? v[2 * k] : v[2 * k + 1];
            v[k] = x + __shfl_xor(y, 2);
        }
        #pragma unroll
        for (int k = 0; k < 2; ++k) {
            float x = (c & 4) ? v[2 * k + 1] : v[2 * k];
            float y = (c & 4) ? v[2 * k] : v[2 * k + 1];
            v[k] = x + __shfl_xor(y, 4);
        }
        {
            float x = (c & 8) ? v[1] : v[0];
            float y = (c & 8) ? v[0] : v[1];
            llds[w][l][t] = (x + __shfl_xor(y, 8)) * 0.0625f;
        }
    }

    // flush: lane (w,rq,c) owns logits[i][b=w*16+rq*4+(c&3)][h=c>>2][jb..jb+7]
    {
        float f[8];
        #pragma unroll
        for (int t2 = 0; t2 < 8; ++t2) f[t2] = llds[w][l][t2];
        const int hh = c >> 2, rr = c & 3;
        const int b = w * 16 + rq * 4 + rr;
        float* dst = &logits[(((size_t)i * B_ + b) * H_ + hh) * S_ + jb];
        *reinterpret_cast<float4*>(dst) = make_float4(f[0], f[1], f[2], f[3]);
        *reinterpret_cast<float4*>(dst + 4) = make_float4(f[4], f[5], f[6], f[7]);
    }
}

// ---------------------------------------------------------------------------
// K2b: softmax over j + PV + out-projection (round-5 version, known-good).
// logits layout [i][b][h][j].
// ---------------------------------------------------------------------------
__global__ __launch_bounds__(256) void k_attn(
    const float* __restrict__ logits, const float* __restrict__ qkv,
    const float* __restrict__ Wout, const float* __restrict__ bout,
    float* __restrict__ out)
{
    __shared__ float wsm[4][H_][S_];
    __shared__ float ap[4][68];
    const int tid = threadIdx.x;
    const int i = blockIdx.x >> 5;
    const int bq = blockIdx.x & 31;
    const int w = tid >> 6, l = tid & 63;
    const int b = bq * 4 + w;

    const float* lg = logits + ((size_t)i * B_ + b) * H_ * S_;
    const int h = l >> 4, sub = l & 15;
    float v0 = lg[h * S_ + sub];
    float v1 = lg[h * S_ + sub + 16];
    float v2 = lg[h * S_ + sub + 32];
    float v3 = lg[h * S_ + sub + 48];
    float m = fmaxf(fmaxf(v0, v1), fmaxf(v2, v3));
    #pragma unroll
    for (int d = 1; d < 16; d <<= 1) m = fmaxf(m, __shfl_xor(m, d));
    float e0 = expf(v0 - m), e1 = expf(v1 - m), e2 = expf(v2 - m), e3 = expf(v3 - m);
    float ss = e0 + e1 + e2 + e3;
    #pragma unroll
    for (int d = 1; d < 16; d <<= 1) ss += __shfl_xor(ss, d);
    float inv = 1.0f / ss;
    wsm[w][h][sub] = e0 * inv;
    wsm[w][h][sub + 16] = e1 * inv;
    wsm[w][h][sub + 32] = e2 * inv;
    wsm[w][h][sub + 48] = e3 * inv;
    __syncthreads();

    const float* vbase = qkv + (size_t)2 * T_ * B_ * E_ + (size_t)b * E_;
    const float* wrow = &wsm[w][l >> 4][0];
    float acc = 0.f;
    #pragma unroll 4
    for (int j = 0; j < S_; ++j) acc += wrow[j] * vbase[(size_t)j * B_ * E_ + l];
    ap[w][l] = acc;
    __syncthreads();

    const float* wo = Wout + l * E_;
    const float* apw = ap[w];
    float oacc = bout[l];
    #pragma unroll 4
    for (int e = 0; e < E_; ++e) oacc += apw[e] * wo[e];
    out[((size_t)i * B_ + b) * E_ + l] = oacc;
}

// ---------------------------------------------------------------------------
extern "C" void kernel_launch(void* const* d_in, const int* in_sizes, int n_in,
                              void* d_out, int out_size, void* d_ws, size_t ws_size,
                              hipStream_t stream)
{
    const float* qin = (const float*)d_in[0];
    const float* kin = (const float*)d_in[1];
    const float* vin = (const float*)d_in[2];
    const float* rel = (const float*)d_in[3];
    const float* ipw = (const float*)d_in[4];
    const float* ipb = (const float*)d_in[5];
    const float* rw  = (const float*)d_in[6];
    const float* rb  = (const float*)d_in[7];
    const float* ow  = (const float*)d_in[8];
    const float* obias = (const float*)d_in[9];

    float* qkv = (float*)d_ws;                        // 3*64*128*64 fl = 6 MB
    float* logits = qkv + 3 * T_ * B_ * E_;           // [i][b][h][j]  = 8 MB
    ushort* wBf  = (ushort*)(logits + (size_t)T_ * S_ * B_ * H_); // 20 KB (+pad)
    ushort* kpbF = wBf + 16384;                       // 64 pages x 16 KB = 1 MB

    float* out = (float*)d_out;

    k_qkv<<<dim3(257), dim3(256), 0, stream>>>(qin, kin, vin, ipw, ipb, qkv,
                                               rw, rb, wBf, (unsigned int*)kpbF);
    k_logits_mfma<<<dim3(512), dim3(512), 0, stream>>>(rel, wBf, kpbF, rb, qkv, logits);
    k_attn<<<dim3(2048), dim3(256), 0, stream>>>(logits, qkv, ow, obias, out);
}